// Round 1
// baseline (321.050 us; speedup 1.0000x reference)
//
#include <hip/hip_runtime.h>
#include <hip/hip_bf16.h>
#include <math.h>

#define Bsz 2
#define Ssz 2048
#define Esz 1024
#define Hsz 16
#define DHsz 64
#define LSTR 72   // padded LDS row stride (elements): 144B, 16B-aligned, breaks bank conflicts

typedef __bf16 bf16_t;
typedef __attribute__((ext_vector_type(8))) __bf16 bf16x8;
typedef __attribute__((ext_vector_type(4))) float f32x4;

__device__ __forceinline__ bf16_t to_bf16(float f) {
  union { float f; unsigned u; } v; v.f = f;
  unsigned r = (v.u + 0x7FFF + ((v.u >> 16) & 1)) >> 16;   // RNE
  union { unsigned short s; bf16_t b; } o; o.s = (unsigned short)r;
  return o.b;
}

__device__ __forceinline__ f32x4 mfma16(bf16x8 a, bf16x8 b, f32x4 c) {
  return __builtin_amdgcn_mfma_f32_16x16x32_bf16(a, b, c, 0, 0, 0);
}

// Stage a 64x64 bf16 tile (row-major, leading dim ld) into LDS with stride LSTR.
__device__ __forceinline__ void stage64(const bf16_t* __restrict__ src, int ld,
                                        bf16_t* __restrict__ dst) {
  const int t = threadIdx.x;       // 256 threads
  const int r = t >> 3;            // 0..31
  const int cc = (t & 7) << 3;     // 0,8,..,56
  *(bf16x8*)&dst[r * LSTR + cc] = *(const bf16x8*)&src[(size_t)r * ld + cc];
  *(bf16x8*)&dst[(r + 32) * LSTR + cc] = *(const bf16x8*)&src[(size_t)(r + 32) * ld + cc];
}

// ---------------- prep kernels ----------------
__global__ void cast_x_kernel(const float* __restrict__ x, bf16_t* __restrict__ xb, int n) {
  int i = blockIdx.x * blockDim.x + threadIdx.x;
  if (i < n) xb[i] = to_bf16(x[i]);
}

// w: [H][E][DH] fp32  ->  wT: [H][DH][E] bf16
__global__ void transpose_whead(const float* __restrict__ w, bf16_t* __restrict__ wT) {
  int i = blockIdx.x * blockDim.x + threadIdx.x;
  if (i < Hsz * Esz * DHsz) {
    int h = i >> 16;          // E*DH = 65536
    int e = (i >> 6) & 1023;
    int d = i & 63;
    wT[((size_t)(h * DHsz + d)) * Esz + e] = to_bf16(w[i]);
  }
}

// wo: [E][E] fp32 -> woT: [n][k] bf16 (woT[n][k] = wo[k][n])
__global__ void transpose_wo_k(const float* __restrict__ wo, bf16_t* __restrict__ woT) {
  int i = blockIdx.x * blockDim.x + threadIdx.x;
  if (i < Esz * Esz) {
    int e = i >> 10, n = i & 1023;
    woT[((size_t)n) * Esz + e] = to_bf16(wo[i]);
  }
}

// ---------------- QKV projection ----------------
// grid: (S/64, H, 6) with z = which*2 + b;   Q,K -> [B][H][S][DH], V -> [B][H][DH][S]
__global__ __launch_bounds__(256) void qkv_gemm(
    const bf16_t* __restrict__ xb, const bf16_t* __restrict__ wT,
    const float* __restrict__ bq, const float* __restrict__ bk, const float* __restrict__ bv,
    bf16_t* __restrict__ qb, bf16_t* __restrict__ kb, bf16_t* __restrict__ vTb) {
  const int stile = blockIdx.x;
  const int h = blockIdx.y;
  const int which = blockIdx.z >> 1;
  const int b = blockIdx.z & 1;
  __shared__ alignas(16) bf16_t lA[64 * LSTR];
  __shared__ alignas(16) bf16_t lB[64 * LSTR];
  const bf16_t* xs = xb + ((size_t)(b * Ssz + stile * 64)) * Esz;
  const bf16_t* ws = wT + (((size_t)which * Hsz + h) * DHsz) * Esz;
  f32x4 acc[4] = {};
  const int lane = threadIdx.x & 63, wv = threadIdx.x >> 6;
  const int g = lane >> 4, c = lane & 15;
  for (int kc = 0; kc < 16; kc++) {
    __syncthreads();
    stage64(xs + kc * 64, Esz, lA);
    stage64(ws + kc * 64, Esz, lB);
    __syncthreads();
#pragma unroll
    for (int ksp = 0; ksp < 2; ksp++) {
      bf16x8 a = *(const bf16x8*)&lA[(wv * 16 + c) * LSTR + ksp * 32 + g * 8];
#pragma unroll
      for (int nt = 0; nt < 4; nt++) {
        bf16x8 bb = *(const bf16x8*)&lB[(nt * 16 + c) * LSTR + ksp * 32 + g * 8];
        acc[nt] = mfma16(a, bb, acc[nt]);
      }
    }
  }
  const float* bias = (which == 0) ? bq : (which == 1) ? bk : bv;
#pragma unroll
  for (int nt = 0; nt < 4; nt++) {
    const int col = nt * 16 + c;
    const float bias_v = bias[h * DHsz + col];
#pragma unroll
    for (int r = 0; r < 4; r++) {
      const int srow = stile * 64 + wv * 16 + g * 4 + r;
      const float val = acc[nt][r] + bias_v;
      if (which == 2) {
        vTb[(((size_t)(b * Hsz + h)) * DHsz + col) * Ssz + srow] = to_bf16(val);
      } else {
        bf16_t* dst = (which == 0) ? qb : kb;
        dst[(((size_t)(b * Hsz + h)) * Ssz + srow) * DHsz + col] = to_bf16(val);
      }
    }
  }
}

// ---------------- flash attention ----------------
// grid: (S/64, H, B).  O -> [B][S][E] bf16 (heads concatenated)
__global__ __launch_bounds__(256) void flash_attn(
    const bf16_t* __restrict__ qb, const bf16_t* __restrict__ kb,
    const bf16_t* __restrict__ vTb, const int* __restrict__ mask,
    bf16_t* __restrict__ Ob) {
  const int qt = blockIdx.x, h = blockIdx.y, b = blockIdx.z;
  __shared__ alignas(16) bf16_t lQ[64 * LSTR];
  __shared__ alignas(16) bf16_t lK[64 * LSTR];
  __shared__ alignas(16) bf16_t lV[64 * LSTR];     // V^T tile: [d][t]
  __shared__ alignas(16) bf16_t lP[4][16 * LSTR];  // per-wave P tiles
  __shared__ float lM[64];
  const size_t bh = (size_t)(b * Hsz + h);
  const bf16_t* qs = qb + (bh * Ssz + qt * 64) * DHsz;
  const bf16_t* ksrc = kb + bh * Ssz * DHsz;
  const bf16_t* vsrc = vTb + bh * DHsz * Ssz;
  const int lane = threadIdx.x & 63, wv = threadIdx.x >> 6;
  const int g = lane >> 4, c = lane & 15;

  stage64(qs, DHsz, lQ);
  f32x4 o[4] = {};
  float m_[4], l_[4];
#pragma unroll
  for (int r = 0; r < 4; r++) { m_[r] = -INFINITY; l_[r] = 0.f; }

  for (int tc = 0; tc < 32; tc++) {
    __syncthreads();
    stage64(ksrc + (size_t)tc * 64 * DHsz, DHsz, lK);
    stage64(vsrc + tc * 64, Ssz, lV);
    if (threadIdx.x < 64)
      lM[threadIdx.x] = (mask[b * Ssz + tc * 64 + threadIdx.x] == 0) ? -1e9f : 0.0f;
    __syncthreads();

    f32x4 s[4] = {};
#pragma unroll
    for (int ksp = 0; ksp < 2; ksp++) {
      bf16x8 a = *(const bf16x8*)&lQ[(wv * 16 + c) * LSTR + ksp * 32 + g * 8];
#pragma unroll
      for (int nt = 0; nt < 4; nt++) {
        bf16x8 bb = *(const bf16x8*)&lK[(nt * 16 + c) * LSTR + ksp * 32 + g * 8];
        s[nt] = mfma16(a, bb, s[nt]);
      }
    }
    float sv[4][4], madd[4];
#pragma unroll
    for (int nt = 0; nt < 4; nt++) madd[nt] = lM[nt * 16 + c];
#pragma unroll
    for (int nt = 0; nt < 4; nt++)
#pragma unroll
      for (int r = 0; r < 4; r++) sv[nt][r] = s[nt][r] * 0.125f + madd[nt];

    float cm[4], rs[4], alpha[4];
#pragma unroll
    for (int r = 0; r < 4; r++)
      cm[r] = fmaxf(fmaxf(sv[0][r], sv[1][r]), fmaxf(sv[2][r], sv[3][r]));
#pragma unroll
    for (int off = 1; off < 16; off <<= 1)
#pragma unroll
      for (int r = 0; r < 4; r++) cm[r] = fmaxf(cm[r], __shfl_xor(cm[r], off));
#pragma unroll
    for (int r = 0; r < 4; r++) {
      float nm = fmaxf(m_[r], cm[r]);
      alpha[r] = __expf(m_[r] - nm);
      m_[r] = nm;
      rs[r] = 0.f;
    }
#pragma unroll
    for (int nt = 0; nt < 4; nt++)
#pragma unroll
      for (int r = 0; r < 4; r++) {
        float p = __expf(sv[nt][r] - m_[r]);
        sv[nt][r] = p;
        rs[r] += p;
      }
#pragma unroll
    for (int off = 1; off < 16; off <<= 1)
#pragma unroll
      for (int r = 0; r < 4; r++) rs[r] += __shfl_xor(rs[r], off);
#pragma unroll
    for (int r = 0; r < 4; r++) l_[r] = l_[r] * alpha[r] + rs[r];
#pragma unroll
    for (int dt = 0; dt < 4; dt++)
#pragma unroll
      for (int r = 0; r < 4; r++) o[dt][r] *= alpha[r];
#pragma unroll
    for (int nt = 0; nt < 4; nt++)
#pragma unroll
      for (int r = 0; r < 4; r++)
        lP[wv][(g * 4 + r) * LSTR + nt * 16 + c] = to_bf16(sv[nt][r]);
    __syncthreads();
#pragma unroll
    for (int ksp = 0; ksp < 2; ksp++) {
      bf16x8 a = *(const bf16x8*)&lP[wv][c * LSTR + ksp * 32 + g * 8];
#pragma unroll
      for (int dt = 0; dt < 4; dt++) {
        bf16x8 bb = *(const bf16x8*)&lV[(dt * 16 + c) * LSTR + ksp * 32 + g * 8];
        o[dt] = mfma16(a, bb, o[dt]);
      }
    }
  }
#pragma unroll
  for (int dt = 0; dt < 4; dt++)
#pragma unroll
    for (int r = 0; r < 4; r++) {
      const int srow = qt * 64 + wv * 16 + g * 4 + r;
      Ob[((size_t)(b * Ssz + srow)) * Esz + h * DHsz + dt * 16 + c] =
          to_bf16(o[dt][r] / l_[r]);
    }
}

// ---------------- output projection ----------------
// grid: (B*S/64, E/64). out = Ob @ wo + bo (fp32 out)
__global__ __launch_bounds__(256) void out_gemm(
    const bf16_t* __restrict__ Ob, const bf16_t* __restrict__ woT,
    const float* __restrict__ bo, float* __restrict__ out) {
  const int mt = blockIdx.x, ntb = blockIdx.y;
  __shared__ alignas(16) bf16_t lA[64 * LSTR];
  __shared__ alignas(16) bf16_t lB[64 * LSTR];
  const bf16_t* asrc = Ob + (size_t)mt * 64 * Esz;
  const bf16_t* bsrc = woT + (size_t)ntb * 64 * Esz;
  f32x4 acc[4] = {};
  const int lane = threadIdx.x & 63, wv = threadIdx.x >> 6;
  const int g = lane >> 4, c = lane & 15;
  for (int kc = 0; kc < 16; kc++) {
    __syncthreads();
    stage64(asrc + kc * 64, Esz, lA);
    stage64(bsrc + kc * 64, Esz, lB);
    __syncthreads();
#pragma unroll
    for (int ksp = 0; ksp < 2; ksp++) {
      bf16x8 a = *(const bf16x8*)&lA[(wv * 16 + c) * LSTR + ksp * 32 + g * 8];
#pragma unroll
      for (int nt = 0; nt < 4; nt++) {
        bf16x8 bb = *(const bf16x8*)&lB[(nt * 16 + c) * LSTR + ksp * 32 + g * 8];
        acc[nt] = mfma16(a, bb, acc[nt]);
      }
    }
  }
#pragma unroll
  for (int nt = 0; nt < 4; nt++) {
    const int col = ntb * 64 + nt * 16 + c;
    const float bias_v = bo[col];
#pragma unroll
    for (int r = 0; r < 4; r++) {
      const int row = mt * 64 + wv * 16 + g * 4 + r;
      out[(size_t)row * Esz + col] = acc[nt][r] + bias_v;
    }
  }
}

extern "C" void kernel_launch(void* const* d_in, const int* in_sizes, int n_in,
                              void* d_out, int out_size, void* d_ws, size_t ws_size,
                              hipStream_t stream) {
  const float* x = (const float*)d_in[0];
  const int* mask = (const int*)d_in[1];
  const float* wq = (const float*)d_in[2];
  const float* bq = (const float*)d_in[3];
  const float* wk = (const float*)d_in[4];
  const float* bk = (const float*)d_in[5];
  const float* wv = (const float*)d_in[6];
  const float* bv = (const float*)d_in[7];
  const float* wo = (const float*)d_in[8];
  const float* bo = (const float*)d_in[9];
  float* out = (float*)d_out;

  char* ws = (char*)d_ws;
  size_t off = 0;
  auto take = [&](size_t bytes) -> char* {
    char* p = ws + off;
    off += (bytes + 255) & ~(size_t)255;
    return p;
  };
  bf16_t* xb = (bf16_t*)take((size_t)Bsz * Ssz * Esz * 2);
  bf16_t* wT = (bf16_t*)take((size_t)3 * Hsz * DHsz * Esz * 2);
  bf16_t* woT = (bf16_t*)take((size_t)Esz * Esz * 2);
  bf16_t* qb = (bf16_t*)take((size_t)Bsz * Hsz * Ssz * DHsz * 2);
  bf16_t* kb = (bf16_t*)take((size_t)Bsz * Hsz * Ssz * DHsz * 2);
  bf16_t* vTb = (bf16_t*)take((size_t)Bsz * Hsz * Ssz * DHsz * 2);
  bf16_t* Ob = (bf16_t*)take((size_t)Bsz * Ssz * Esz * 2);

  const int nx = Bsz * Ssz * Esz;
  cast_x_kernel<<<(nx + 255) / 256, 256, 0, stream>>>(x, xb, nx);
  const int wn = Hsz * Esz * DHsz;
  const size_t wstride = (size_t)Hsz * DHsz * Esz;
  transpose_whead<<<(wn + 255) / 256, 256, 0, stream>>>(wq, wT + 0 * wstride);
  transpose_whead<<<(wn + 255) / 256, 256, 0, stream>>>(wk, wT + 1 * wstride);
  transpose_whead<<<(wn + 255) / 256, 256, 0, stream>>>(wv, wT + 2 * wstride);
  transpose_wo_k<<<(Esz * Esz + 255) / 256, 256, 0, stream>>>(wo, woT);

  qkv_gemm<<<dim3(Ssz / 64, Hsz, 6), 256, 0, stream>>>(xb, wT, bq, bk, bv, qb, kb, vTb);
  flash_attn<<<dim3(Ssz / 64, Hsz, Bsz), 256, 0, stream>>>(qb, kb, vTb, mask, Ob);
  out_gemm<<<dim3(Bsz * Ssz / 64, Esz / 64), 256, 0, stream>>>(Ob, woT, bo, out);
}

// Round 2
// 256.072 us; speedup vs baseline: 1.2537x; 1.2537x over previous
//
#include <hip/hip_runtime.h>
#include <hip/hip_bf16.h>
#include <math.h>

#define Bsz 2
#define Ssz 2048
#define Esz 1024
#define Hsz 16
#define DHsz 64
#define LSTR 72   // padded LDS row stride for the GEMM kernels (unchanged from R1)

typedef __bf16 bf16_t;
typedef __attribute__((ext_vector_type(8))) __bf16 bf16x8;
typedef __attribute__((ext_vector_type(4))) float f32x4;

typedef unsigned int u32;
typedef const __attribute__((address_space(1))) u32* gptr_t;
typedef __attribute__((address_space(3))) u32* lptr_t;

#if __has_builtin(__builtin_amdgcn_exp2f)
#define EXP2F(x) __builtin_amdgcn_exp2f(x)
#else
#define EXP2F(x) __expf((x)*0.69314718f)
#endif

__device__ __forceinline__ bf16_t to_bf16(float f) {
  union { float f; unsigned u; } v; v.f = f;
  unsigned r = (v.u + 0x7FFF + ((v.u >> 16) & 1)) >> 16;   // RNE
  union { unsigned short s; bf16_t b; } o; o.s = (unsigned short)r;
  return o.b;
}

// pack two non-negative floats to 2 bf16 (RNE) in one u32
__device__ __forceinline__ unsigned pack2(float a, float b) {
  union { float f; unsigned u; } x, y; x.f = a; y.f = b;
  unsigned ra = (x.u + 0x7FFF + ((x.u >> 16) & 1)) >> 16;
  unsigned rb = (y.u + 0x7FFF + ((y.u >> 16) & 1)) >> 16;
  return ra | (rb << 16);
}

__device__ __forceinline__ f32x4 mfma16(bf16x8 a, bf16x8 b, f32x4 c) {
  return __builtin_amdgcn_mfma_f32_16x16x32_bf16(a, b, c, 0, 0, 0);
}

// async global->LDS, 16B per lane; lds base must be wave-uniform
__device__ __forceinline__ void gload16(void* lds, const void* g) {
  __builtin_amdgcn_global_load_lds((gptr_t)g, (lptr_t)lds, 16, 0, 0);
}

// Stage a 64x64 bf16 tile (row-major, leading dim ld) into LDS with stride LSTR.
__device__ __forceinline__ void stage64(const bf16_t* __restrict__ src, int ld,
                                        bf16_t* __restrict__ dst) {
  const int t = threadIdx.x;       // 256 threads
  const int r = t >> 3;            // 0..31
  const int cc = (t & 7) << 3;     // 0,8,..,56
  *(bf16x8*)&dst[r * LSTR + cc] = *(const bf16x8*)&src[(size_t)r * ld + cc];
  *(bf16x8*)&dst[(r + 32) * LSTR + cc] = *(const bf16x8*)&src[(size_t)(r + 32) * ld + cc];
}

// ---------------- prep kernels ----------------
__global__ void cast_x_kernel(const float* __restrict__ x, bf16_t* __restrict__ xb, int n) {
  int i = blockIdx.x * blockDim.x + threadIdx.x;
  if (i < n) xb[i] = to_bf16(x[i]);
}

// w: [H][E][DH] fp32  ->  wT: [H][DH][E] bf16
__global__ void transpose_whead(const float* __restrict__ w, bf16_t* __restrict__ wT) {
  int i = blockIdx.x * blockDim.x + threadIdx.x;
  if (i < Hsz * Esz * DHsz) {
    int h = i >> 16;          // E*DH = 65536
    int e = (i >> 6) & 1023;
    int d = i & 63;
    wT[((size_t)(h * DHsz + d)) * Esz + e] = to_bf16(w[i]);
  }
}

// wo: [E][E] fp32 -> woT: [n][k] bf16 (woT[n][k] = wo[k][n])
__global__ void transpose_wo_k(const float* __restrict__ wo, bf16_t* __restrict__ woT) {
  int i = blockIdx.x * blockDim.x + threadIdx.x;
  if (i < Esz * Esz) {
    int e = i >> 10, n = i & 1023;
    woT[((size_t)n) * Esz + e] = to_bf16(wo[i]);
  }
}

// ---------------- QKV projection ----------------
// grid: (S/64, H, 6) with z = which*2 + b;   Q,K -> [B][H][S][DH], V -> [B][H][DH][S]
// Q is pre-scaled by 0.125*log2(e) so flash_attn can use raw exp2.
__global__ __launch_bounds__(256) void qkv_gemm(
    const bf16_t* __restrict__ xb, const bf16_t* __restrict__ wT,
    const float* __restrict__ bq, const float* __restrict__ bk, const float* __restrict__ bv,
    bf16_t* __restrict__ qb, bf16_t* __restrict__ kb, bf16_t* __restrict__ vTb) {
  const int stile = blockIdx.x;
  const int h = blockIdx.y;
  const int which = blockIdx.z >> 1;
  const int b = blockIdx.z & 1;
  __shared__ alignas(16) bf16_t lA[64 * LSTR];
  __shared__ alignas(16) bf16_t lB[64 * LSTR];
  const bf16_t* xs = xb + ((size_t)(b * Ssz + stile * 64)) * Esz;
  const bf16_t* ws = wT + (((size_t)which * Hsz + h) * DHsz) * Esz;
  f32x4 acc[4] = {};
  const int lane = threadIdx.x & 63, wv = threadIdx.x >> 6;
  const int g = lane >> 4, c = lane & 15;
  for (int kc = 0; kc < 16; kc++) {
    __syncthreads();
    stage64(xs + kc * 64, Esz, lA);
    stage64(ws + kc * 64, Esz, lB);
    __syncthreads();
#pragma unroll
    for (int ksp = 0; ksp < 2; ksp++) {
      bf16x8 a = *(const bf16x8*)&lA[(wv * 16 + c) * LSTR + ksp * 32 + g * 8];
#pragma unroll
      for (int nt = 0; nt < 4; nt++) {
        bf16x8 bb = *(const bf16x8*)&lB[(nt * 16 + c) * LSTR + ksp * 32 + g * 8];
        acc[nt] = mfma16(a, bb, acc[nt]);
      }
    }
  }
  const float* bias = (which == 0) ? bq : (which == 1) ? bk : bv;
#pragma unroll
  for (int nt = 0; nt < 4; nt++) {
    const int col = nt * 16 + c;
    const float bias_v = bias[h * DHsz + col];
#pragma unroll
    for (int r = 0; r < 4; r++) {
      const int srow = stile * 64 + wv * 16 + g * 4 + r;
      float val = acc[nt][r] + bias_v;
      if (which == 0) val *= 0.18033688011112042f;  // 0.125*log2(e)
      if (which == 2) {
        vTb[(((size_t)(b * Hsz + h)) * DHsz + col) * Ssz + srow] = to_bf16(val);
      } else {
        bf16_t* dst = (which == 0) ? qb : kb;
        dst[(((size_t)(b * Hsz + h)) * Ssz + srow) * DHsz + col] = to_bf16(val);
      }
    }
  }
}

// ---------------- flash attention (S^T formulation, swizzled LDS) ----------------
// grid: (S/128, H, B), 256 threads. Each wave: 32 q rows x 64 keys per iter.
// K/V tiles: unpadded 64x64 in LDS, 16B-granule phys = logical ^ (row&7).
__global__ __launch_bounds__(256, 2) void flash_attn(
    const bf16_t* __restrict__ qb, const bf16_t* __restrict__ kb,
    const bf16_t* __restrict__ vTb, const int* __restrict__ mask,
    bf16_t* __restrict__ Ob) {
  __shared__ alignas(16) bf16_t lK0[64 * 64];
  __shared__ alignas(16) bf16_t lV0[64 * 64];
  __shared__ alignas(16) bf16_t lK1[64 * 64];
  __shared__ alignas(16) bf16_t lV1[64 * 64];
  __shared__ alignas(16) bf16_t lP[4][32 * 64];
  __shared__ float lMask[Ssz];
  __shared__ float lL[4][32];

  const int qt = blockIdx.x, h = blockIdx.y, b = blockIdx.z;
  const size_t bh = (size_t)(b * Hsz + h);
  const int tid = threadIdx.x, lane = tid & 63, wv = tid >> 6;
  const int g = lane >> 4, c = lane & 15, cw = c & 7;
  const int lrow = lane >> 3, sg = lane & 7;
  const int kg = sg ^ lrow;     // swizzled source granule for staging

  const bf16_t* Kbase = kb + bh * (size_t)Ssz * DHsz;
  const bf16_t* Vbase = vTb + bh * (size_t)DHsz * Ssz;

  // mask -> 0/1 floats in LDS (once)
  for (int i = tid; i < Ssz; i += 256) lMask[i] = mask[b * Ssz + i] ? 1.0f : 0.0f;

  // Q fragments in registers (B-operand), loaded once
  bf16x8 qf[2][2];
  const bf16_t* Qbase = qb + (bh * Ssz + qt * 128 + wv * 32) * DHsz;
#pragma unroll
  for (int qsub = 0; qsub < 2; qsub++)
#pragma unroll
    for (int ksp = 0; ksp < 2; ksp++)
      qf[qsub][ksp] = *(const bf16x8*)&Qbase[(qsub * 16 + c) * DHsz + ksp * 32 + g * 8];

  f32x4 o[2][4] = {};
  float lacc[2] = {0.f, 0.f};

  auto stage = [&](bf16_t* dK, bf16_t* dV, int tc) {
#pragma unroll
    for (int j = 0; j < 2; j++) {
      const int row = wv * 16 + j * 8 + lrow;
      gload16(dK + (wv * 16 + j * 8) * 64,
              Kbase + ((size_t)(tc * 64 + row)) * DHsz + kg * 8);
      gload16(dV + (wv * 16 + j * 8) * 64,
              Vbase + (size_t)row * Ssz + tc * 64 + kg * 8);
    }
  };

  auto compute = [&](const bf16_t* Kt, const bf16_t* Vt, int tc) {
#pragma unroll
    for (int qsub = 0; qsub < 2; qsub++) {
      f32x4 st[4] = {};
#pragma unroll
      for (int ksp = 0; ksp < 2; ksp++) {
        const int kgr = (ksp * 4 + g) ^ cw;
#pragma unroll
        for (int nt = 0; nt < 4; nt++) {
          bf16x8 kf = *(const bf16x8*)&Kt[(nt * 16 + c) * 64 + kgr * 8];
          st[nt] = mfma16(kf, qf[qsub][ksp], st[nt]);   // S^T: row=key, col=q
        }
      }
      float part = 0.f;
#pragma unroll
      for (int nt = 0; nt < 4; nt++) {
        const float4 mv = *(const float4*)&lMask[tc * 64 + nt * 16 + g * 4];
        float p0 = EXP2F(st[nt][0]) * mv.x;
        float p1 = EXP2F(st[nt][1]) * mv.y;
        float p2 = EXP2F(st[nt][2]) * mv.z;
        float p3 = EXP2F(st[nt][3]) * mv.w;
        part += (p0 + p1) + (p2 + p3);
        const int pg = (nt * 2 + (g >> 1)) ^ cw;
        uint2 pv; pv.x = pack2(p0, p1); pv.y = pack2(p2, p3);
        *(uint2*)&lP[wv][(qsub * 16 + c) * 64 + pg * 8 + (g & 1) * 4] = pv;
      }
      lacc[qsub] += part;
      // PV: per-wave lP, no barrier needed (same-wave DS ordering)
#pragma unroll
      for (int ksp = 0; ksp < 2; ksp++) {
        const int kgr = (ksp * 4 + g) ^ cw;
        bf16x8 pf = *(const bf16x8*)&lP[wv][(qsub * 16 + c) * 64 + kgr * 8];
#pragma unroll
        for (int dt = 0; dt < 4; dt++) {
          bf16x8 vf = *(const bf16x8*)&Vt[(dt * 16 + c) * 64 + kgr * 8];
          o[qsub][dt] = mfma16(pf, vf, o[qsub][dt]);
        }
      }
    }
  };

  stage(lK0, lV0, 0);
  __syncthreads();
  for (int tc = 0; tc < 32; tc += 2) {
    stage(lK1, lV1, tc + 1);
    compute(lK0, lV0, tc);
    __syncthreads();
    if (tc + 2 < 32) stage(lK0, lV0, tc + 2);
    compute(lK1, lV1, tc + 1);
    __syncthreads();
  }

  // softmax denominator: reduce over the 4 g-lanes sharing a q column
#pragma unroll
  for (int qsub = 0; qsub < 2; qsub++) {
    float v = lacc[qsub];
    v += __shfl_xor(v, 16);
    v += __shfl_xor(v, 32);
    lL[wv][qsub * 16 + c] = v;
  }
  // epilogue: O row = qsub*16 + g*4 + r, col = dt*16 + c
#pragma unroll
  for (int qsub = 0; qsub < 2; qsub++)
#pragma unroll
    for (int r = 0; r < 4; r++) {
      const int row = qsub * 16 + g * 4 + r;
      const float linv = 1.0f / fmaxf(lL[wv][row], 1e-30f);
      const size_t orow = (size_t)(b * Ssz + qt * 128 + wv * 32 + row) * Esz + h * DHsz;
#pragma unroll
      for (int dt = 0; dt < 4; dt++)
        Ob[orow + dt * 16 + c] = to_bf16(o[qsub][dt][r] * linv);
    }
}

// ---------------- output projection ----------------
// grid: (B*S/64, E/64). out = Ob @ wo + bo (fp32 out)
__global__ __launch_bounds__(256) void out_gemm(
    const bf16_t* __restrict__ Ob, const bf16_t* __restrict__ woT,
    const float* __restrict__ bo, float* __restrict__ out) {
  const int mt = blockIdx.x, ntb = blockIdx.y;
  __shared__ alignas(16) bf16_t lA[64 * LSTR];
  __shared__ alignas(16) bf16_t lB[64 * LSTR];
  const bf16_t* asrc = Ob + (size_t)mt * 64 * Esz;
  const bf16_t* bsrc = woT + (size_t)ntb * 64 * Esz;
  f32x4 acc[4] = {};
  const int lane = threadIdx.x & 63, wv = threadIdx.x >> 6;
  const int g = lane >> 4, c = lane & 15;
  for (int kc = 0; kc < 16; kc++) {
    __syncthreads();
    stage64(asrc + kc * 64, Esz, lA);
    stage64(bsrc + kc * 64, Esz, lB);
    __syncthreads();
#pragma unroll
    for (int ksp = 0; ksp < 2; ksp++) {
      bf16x8 a = *(const bf16x8*)&lA[(wv * 16 + c) * LSTR + ksp * 32 + g * 8];
#pragma unroll
      for (int nt = 0; nt < 4; nt++) {
        bf16x8 bb = *(const bf16x8*)&lB[(nt * 16 + c) * LSTR + ksp * 32 + g * 8];
        acc[nt] = mfma16(a, bb, acc[nt]);
      }
    }
  }
#pragma unroll
  for (int nt = 0; nt < 4; nt++) {
    const int col = ntb * 64 + nt * 16 + c;
    const float bias_v = bo[col];
#pragma unroll
    for (int r = 0; r < 4; r++) {
      const int row = mt * 64 + wv * 16 + g * 4 + r;
      out[(size_t)row * Esz + col] = acc[nt][r] + bias_v;
    }
  }
}

extern "C" void kernel_launch(void* const* d_in, const int* in_sizes, int n_in,
                              void* d_out, int out_size, void* d_ws, size_t ws_size,
                              hipStream_t stream) {
  const float* x = (const float*)d_in[0];
  const int* mask = (const int*)d_in[1];
  const float* wq = (const float*)d_in[2];
  const float* bq = (const float*)d_in[3];
  const float* wk = (const float*)d_in[4];
  const float* bk = (const float*)d_in[5];
  const float* wv = (const float*)d_in[6];
  const float* bv = (const float*)d_in[7];
  const float* wo = (const float*)d_in[8];
  const float* bo = (const float*)d_in[9];
  float* out = (float*)d_out;

  char* ws = (char*)d_ws;
  size_t off = 0;
  auto take = [&](size_t bytes) -> char* {
    char* p = ws + off;
    off += (bytes + 255) & ~(size_t)255;
    return p;
  };
  bf16_t* xb = (bf16_t*)take((size_t)Bsz * Ssz * Esz * 2);
  bf16_t* wT = (bf16_t*)take((size_t)3 * Hsz * DHsz * Esz * 2);
  bf16_t* woT = (bf16_t*)take((size_t)Esz * Esz * 2);
  bf16_t* qb = (bf16_t*)take((size_t)Bsz * Hsz * Ssz * DHsz * 2);
  bf16_t* kb = (bf16_t*)take((size_t)Bsz * Hsz * Ssz * DHsz * 2);
  bf16_t* vTb = (bf16_t*)take((size_t)Bsz * Hsz * Ssz * DHsz * 2);
  bf16_t* Ob = (bf16_t*)take((size_t)Bsz * Ssz * Esz * 2);

  const int nx = Bsz * Ssz * Esz;
  cast_x_kernel<<<(nx + 255) / 256, 256, 0, stream>>>(x, xb, nx);
  const int wn = Hsz * Esz * DHsz;
  const size_t wstride = (size_t)Hsz * DHsz * Esz;
  transpose_whead<<<(wn + 255) / 256, 256, 0, stream>>>(wq, wT + 0 * wstride);
  transpose_whead<<<(wn + 255) / 256, 256, 0, stream>>>(wk, wT + 1 * wstride);
  transpose_whead<<<(wn + 255) / 256, 256, 0, stream>>>(wv, wT + 2 * wstride);
  transpose_wo_k<<<(Esz * Esz + 255) / 256, 256, 0, stream>>>(wo, woT);

  qkv_gemm<<<dim3(Ssz / 64, Hsz, 6), 256, 0, stream>>>(xb, wT, bq, bk, bv, qb, kb, vTb);
  flash_attn<<<dim3(Ssz / 128, Hsz, Bsz), 256, 0, stream>>>(qb, kb, vTb, mask, Ob);
  out_gemm<<<dim3(Bsz * Ssz / 64, Esz / 64), 256, 0, stream>>>(Ob, woT, bo, out);
}

// Round 3
// 212.793 us; speedup vs baseline: 1.5087x; 1.2034x over previous
//
#include <hip/hip_runtime.h>
#include <hip/hip_bf16.h>
#include <math.h>

#define Bsz 2
#define Ssz 2048
#define Esz 1024
#define Hsz 16
#define DHsz 64

typedef __bf16 bf16_t;
typedef __attribute__((ext_vector_type(8))) __bf16 bf16x8;
typedef __attribute__((ext_vector_type(4))) float f32x4;

typedef unsigned int u32;
typedef const __attribute__((address_space(1))) u32* gptr_t;
typedef __attribute__((address_space(3))) u32* lptr_t;

#if __has_builtin(__builtin_amdgcn_exp2f)
#define EXP2F(x) __builtin_amdgcn_exp2f(x)
#else
#define EXP2F(x) __expf((x)*0.69314718f)
#endif

__device__ __forceinline__ bf16_t to_bf16(float f) {
  union { float f; unsigned u; } v; v.f = f;
  unsigned r = (v.u + 0x7FFF + ((v.u >> 16) & 1)) >> 16;   // RNE
  union { unsigned short s; bf16_t b; } o; o.s = (unsigned short)r;
  return o.b;
}

__device__ __forceinline__ unsigned pack2(float a, float b) {
  union { float f; unsigned u; } x, y; x.f = a; y.f = b;
  unsigned ra = (x.u + 0x7FFF + ((x.u >> 16) & 1)) >> 16;
  unsigned rb = (y.u + 0x7FFF + ((y.u >> 16) & 1)) >> 16;
  return ra | (rb << 16);
}

__device__ __forceinline__ f32x4 mfma16(bf16x8 a, bf16x8 b, f32x4 c) {
  return __builtin_amdgcn_mfma_f32_16x16x32_bf16(a, b, c, 0, 0, 0);
}

// async global->LDS, 16B per lane; lds base must be wave-uniform
__device__ __forceinline__ void gload16(void* lds, const void* g) {
  __builtin_amdgcn_global_load_lds((gptr_t)g, (lptr_t)lds, 16, 0, 0);
}

// ---------------- prep kernels ----------------
__global__ void cast_x4(const float4* __restrict__ x, uint2* __restrict__ xb, int n4) {
  int i = blockIdx.x * blockDim.x + threadIdx.x;
  if (i < n4) {
    float4 v = x[i];
    uint2 o; o.x = pack2(v.x, v.y); o.y = pack2(v.z, v.w);
    xb[i] = o;
  }
}

__global__ void mask_f(const int* __restrict__ mask, float* __restrict__ mf, int n) {
  int i = blockIdx.x * blockDim.x + threadIdx.x;
  if (i < n) mf[i] = mask[i] ? 1.0f : 0.0f;
}

// LDS-tiled transpose+cast of one 64x64 fp32 tile.
// z: 0=wq->wAll[0..1023], 1=wk->wAll[1024..2047], 2=wv->wAllV, 3=wo->woT
__global__ __launch_bounds__(256) void wtrans(
    const float* __restrict__ wq, const float* __restrict__ wk,
    const float* __restrict__ wv, const float* __restrict__ wo,
    bf16_t* __restrict__ wAll, bf16_t* __restrict__ wAllV, bf16_t* __restrict__ woT) {
  __shared__ bf16_t lT[64 * 72];
  const int et = blockIdx.x, h = blockIdx.y, z = blockIdx.z;
  const float* src; int srcLD; bf16_t* dst;
  if (z == 0)      { src = wq + ((size_t)h * Esz + et * 64) * DHsz; srcLD = DHsz; dst = wAll  + (size_t)(h * 64) * Esz; }
  else if (z == 1) { src = wk + ((size_t)h * Esz + et * 64) * DHsz; srcLD = DHsz; dst = wAll  + (size_t)(1024 + h * 64) * Esz; }
  else if (z == 2) { src = wv + ((size_t)h * Esz + et * 64) * DHsz; srcLD = DHsz; dst = wAllV + (size_t)(h * 64) * Esz; }
  else             { src = wo + (size_t)(et * 64) * Esz + h * 64;   srcLD = Esz;  dst = woT   + (size_t)(h * 64) * Esz; }
  const int t = threadIdx.x;
#pragma unroll
  for (int rr = 0; rr < 4; rr++) {
    int er = rr * 16 + (t >> 4);
    int dc = (t & 15) * 4;
    float4 v = *(const float4*)&src[(size_t)er * srcLD + dc];
    lT[(dc + 0) * 72 + er] = to_bf16(v.x);
    lT[(dc + 1) * 72 + er] = to_bf16(v.y);
    lT[(dc + 2) * 72 + er] = to_bf16(v.z);
    lT[(dc + 3) * 72 + er] = to_bf16(v.w);
  }
  __syncthreads();
#pragma unroll
  for (int rr = 0; rr < 2; rr++) {
    int d = rr * 32 + (t >> 3);
    int e8 = (t & 7) * 8;
    bf16x8 o = *(const bf16x8*)&lT[d * 72 + e8];
    *(bf16x8*)&dst[(size_t)d * Esz + et * 64 + e8] = o;
  }
}

// ---------------- generic m97-style GEMM core ----------------
// C[TM x TN] += A[TM x K] . B[TN x K]^T, both row-major (K contiguous).
// 256 threads, waves 2x2, XOR-swizzled LDS, global_load_lds staging.
template <int TM, int TN>
__device__ __forceinline__ void gemm_core(
    const bf16_t* __restrict__ Ab, const bf16_t* __restrict__ Bb, int K,
    bf16_t* lA, bf16_t* lB, f32x4 (&acc)[TM / 32][TN / 32]) {
  const int tid = threadIdx.x, lane = tid & 63, wvi = tid >> 6;
  const int g = lane >> 4, c = lane & 15, cw = c & 7;
  const int lrow = lane >> 3, sg = lane & 7;
  const int wm = wvi >> 1, wn = wvi & 1;
  for (int kc = 0; kc < K; kc += 64) {
#pragma unroll
    for (int j = 0; j < TM / 32; j++) {
      const int base = (j * 4 + wvi) * 8;
      const int row = base + lrow;
      gload16(lA + base * 64, Ab + (size_t)row * K + kc + ((sg ^ (row & 7)) * 8));
    }
#pragma unroll
    for (int j = 0; j < TN / 32; j++) {
      const int base = (j * 4 + wvi) * 8;
      const int row = base + lrow;
      gload16(lB + base * 64, Bb + (size_t)row * K + kc + ((sg ^ (row & 7)) * 8));
    }
    __syncthreads();
#pragma unroll
    for (int ksp = 0; ksp < 2; ksp++) {
      const int kg = (ksp * 4 + g) ^ cw;
      bf16x8 af[TM / 32], bfr[TN / 32];
#pragma unroll
      for (int mt = 0; mt < TM / 32; mt++)
        af[mt] = *(const bf16x8*)&lA[(wm * (TM / 2) + mt * 16 + c) * 64 + kg * 8];
#pragma unroll
      for (int nt = 0; nt < TN / 32; nt++)
        bfr[nt] = *(const bf16x8*)&lB[(wn * (TN / 2) + nt * 16 + c) * 64 + kg * 8];
#pragma unroll
      for (int mt = 0; mt < TM / 32; mt++)
#pragma unroll
        for (int nt = 0; nt < TN / 32; nt++)
          acc[mt][nt] = mfma16(af[mt], bfr[nt], acc[mt][nt]);
    }
    __syncthreads();
  }
}

// ---------------- Q,K projection (fused heads) ----------------
// C = xb[4096 x 1024] . wAll[2048 x 1024]^T; cols: which=n>>10, h=(n>>6)&15, d=n&63
__global__ __launch_bounds__(256, 2) void qk_gemm(
    const bf16_t* __restrict__ xb, const bf16_t* __restrict__ wAll,
    const float* __restrict__ bq, const float* __restrict__ bk,
    bf16_t* __restrict__ qb, bf16_t* __restrict__ kb) {
  __shared__ alignas(16) bf16_t lA[128 * 64];
  __shared__ alignas(16) bf16_t lB[128 * 64];
  f32x4 acc[4][4] = {};
  const int Mb = blockIdx.x * 128, Nb = blockIdx.y * 128;
  gemm_core<128, 128>(xb + (size_t)Mb * Esz, wAll + (size_t)Nb * Esz, Esz, lA, lB, acc);
  const int lane = threadIdx.x & 63, wvi = threadIdx.x >> 6;
  const int g = lane >> 4, c = lane & 15;
  const int wm = wvi >> 1, wn = wvi & 1;
#pragma unroll
  for (int nt = 0; nt < 4; nt++) {
    const int col = Nb + wn * 64 + nt * 16 + c;
    const int which = col >> 10, h = (col >> 6) & 15, d = col & 63;
    const float bias = (which ? bk : bq)[h * DHsz + d];
    const float scale = which ? 1.0f : 0.18033688011112042f;  // 0.125*log2(e)
    bf16_t* dst = which ? kb : qb;
#pragma unroll
    for (int mt = 0; mt < 4; mt++)
#pragma unroll
      for (int r = 0; r < 4; r++) {
        const int row = Mb + wm * 64 + mt * 16 + g * 4 + r;
        const int b = row >> 11, s = row & 2047;
        dst[(((size_t)(b * Hsz + h)) * Ssz + s) * DHsz + d] =
            to_bf16((acc[mt][nt][r] + bias) * scale);
      }
  }
}

// ---------------- V^T projection ----------------
// C = wAllV[1024 x 1024] . xb_b[2048 x 1024]^T  -> vT[b][h][d][s]
__global__ __launch_bounds__(256, 2) void vt_gemm(
    const bf16_t* __restrict__ xb, const bf16_t* __restrict__ wAllV,
    const float* __restrict__ bv, bf16_t* __restrict__ vTb) {
  __shared__ alignas(16) bf16_t lA[64 * 64];
  __shared__ alignas(16) bf16_t lB[128 * 64];
  f32x4 acc[2][4] = {};
  const int Mb = blockIdx.x * 64, Nb = blockIdx.y * 128, b = blockIdx.z;
  gemm_core<64, 128>(wAllV + (size_t)Mb * Esz, xb + ((size_t)(b * Ssz) + Nb) * Esz,
                     Esz, lA, lB, acc);
  const int lane = threadIdx.x & 63, wvi = threadIdx.x >> 6;
  const int g = lane >> 4, c = lane & 15;
  const int wm = wvi >> 1, wn = wvi & 1;
#pragma unroll
  for (int mt = 0; mt < 2; mt++)
#pragma unroll
    for (int r = 0; r < 4; r++) {
      const int m = Mb + wm * 32 + mt * 16 + g * 4 + r;   // = h*64+d
      const float bias = bv[m];
      const size_t obase = ((size_t)(b * Hsz * DHsz + m)) * Ssz;
#pragma unroll
      for (int nt = 0; nt < 4; nt++) {
        const int s = Nb + wn * 64 + nt * 16 + c;
        vTb[obase + s] = to_bf16(acc[mt][nt][r] + bias);
      }
    }
}

// ---------------- flash attention ----------------
// grid: (H, S/128, B). K/V LDS swizzled; P per-wave; mask from global floats.
__global__ __launch_bounds__(256, 3) void flash_attn(
    const bf16_t* __restrict__ qb, const bf16_t* __restrict__ kb,
    const bf16_t* __restrict__ vTb, const float* __restrict__ mf,
    bf16_t* __restrict__ Ob) {
  __shared__ alignas(16) bf16_t lK0[64 * 64];
  __shared__ alignas(16) bf16_t lV0[64 * 64];
  __shared__ alignas(16) bf16_t lK1[64 * 64];
  __shared__ alignas(16) bf16_t lV1[64 * 64];
  __shared__ alignas(16) bf16_t lP[4][32 * 64];
  __shared__ float lL[4][32];

  const int h = blockIdx.x, qt = blockIdx.y, b = blockIdx.z;  // h fastest -> XCD affinity
  const size_t bh = (size_t)(b * Hsz + h);
  const int tid = threadIdx.x, lane = tid & 63, wv = tid >> 6;
  const int g = lane >> 4, c = lane & 15, cw = c & 7;
  const int lrow = lane >> 3, sg = lane & 7;

  const bf16_t* Kbase = kb + bh * (size_t)Ssz * DHsz;
  const bf16_t* Vbase = vTb + bh * (size_t)DHsz * Ssz;
  const float* mbase = mf + b * Ssz;

  bf16x8 qf[2][2];
  const bf16_t* Qbase = qb + (bh * Ssz + qt * 128 + wv * 32) * DHsz;
#pragma unroll
  for (int qsub = 0; qsub < 2; qsub++)
#pragma unroll
    for (int ksp = 0; ksp < 2; ksp++)
      qf[qsub][ksp] = *(const bf16x8*)&Qbase[(qsub * 16 + c) * DHsz + ksp * 32 + g * 8];

  f32x4 o[2][4] = {};
  float lacc[2] = {0.f, 0.f};

  auto stage = [&](bf16_t* dK, bf16_t* dV, int tc) {
#pragma unroll
    for (int j = 0; j < 2; j++) {
      const int row = wv * 16 + j * 8 + lrow;
      const int kg = sg ^ (row & 7);
      gload16(dK + (wv * 16 + j * 8) * 64,
              Kbase + ((size_t)(tc * 64 + row)) * DHsz + kg * 8);
      gload16(dV + (wv * 16 + j * 8) * 64,
              Vbase + (size_t)row * Ssz + tc * 64 + kg * 8);
    }
  };

  auto compute = [&](const bf16_t* Kt, const bf16_t* Vt, int tc) {
    f32x4 st[2][4] = {};
#pragma unroll
    for (int ksp = 0; ksp < 2; ksp++) {
      const int kgr = (ksp * 4 + g) ^ cw;
#pragma unroll
      for (int nt = 0; nt < 4; nt++) {
        bf16x8 kf = *(const bf16x8*)&Kt[(nt * 16 + c) * 64 + kgr * 8];
        st[0][nt] = mfma16(kf, qf[0][ksp], st[0][nt]);
        st[1][nt] = mfma16(kf, qf[1][ksp], st[1][nt]);
      }
    }
    float4 mv[4];
#pragma unroll
    for (int nt = 0; nt < 4; nt++)
      mv[nt] = *(const float4*)&mbase[tc * 64 + nt * 16 + g * 4];
#pragma unroll
    for (int qsub = 0; qsub < 2; qsub++) {
      float part = 0.f;
#pragma unroll
      for (int nt = 0; nt < 4; nt++) {
        float p0 = EXP2F(st[qsub][nt][0]) * mv[nt].x;
        float p1 = EXP2F(st[qsub][nt][1]) * mv[nt].y;
        float p2 = EXP2F(st[qsub][nt][2]) * mv[nt].z;
        float p3 = EXP2F(st[qsub][nt][3]) * mv[nt].w;
        part += (p0 + p1) + (p2 + p3);
        const int pg = (nt * 2 + (g >> 1)) ^ cw;
        uint2 pv; pv.x = pack2(p0, p1); pv.y = pack2(p2, p3);
        *(uint2*)&lP[wv][(qsub * 16 + c) * 64 + pg * 8 + (g & 1) * 4] = pv;
      }
      lacc[qsub] += part;
    }
    // PV: per-wave lP, same-wave DS ordering, no barrier
#pragma unroll
    for (int ksp = 0; ksp < 2; ksp++) {
      const int kgr = (ksp * 4 + g) ^ cw;
      bf16x8 pf0 = *(const bf16x8*)&lP[wv][(0 * 16 + c) * 64 + kgr * 8];
      bf16x8 pf1 = *(const bf16x8*)&lP[wv][(1 * 16 + c) * 64 + kgr * 8];
#pragma unroll
      for (int dt = 0; dt < 4; dt++) {
        bf16x8 vf = *(const bf16x8*)&Vt[(dt * 16 + c) * 64 + kgr * 8];
        o[0][dt] = mfma16(pf0, vf, o[0][dt]);
        o[1][dt] = mfma16(pf1, vf, o[1][dt]);
      }
    }
  };

  stage(lK0, lV0, 0);
  __syncthreads();
  for (int tc = 0; tc < 32; tc += 2) {
    stage(lK1, lV1, tc + 1);
    compute(lK0, lV0, tc);
    __syncthreads();
    if (tc + 2 < 32) stage(lK0, lV0, tc + 2);
    compute(lK1, lV1, tc + 1);
    __syncthreads();
  }

#pragma unroll
  for (int qsub = 0; qsub < 2; qsub++) {
    float v = lacc[qsub];
    v += __shfl_xor(v, 16);
    v += __shfl_xor(v, 32);
    lL[wv][qsub * 16 + c] = v;
  }
#pragma unroll
  for (int qsub = 0; qsub < 2; qsub++)
#pragma unroll
    for (int r = 0; r < 4; r++) {
      const int row = qsub * 16 + g * 4 + r;
      const float linv = 1.0f / fmaxf(lL[wv][row], 1e-30f);
      const size_t orow = (size_t)(b * Ssz + qt * 128 + wv * 32 + row) * Esz + h * DHsz;
#pragma unroll
      for (int dt = 0; dt < 4; dt++)
        Ob[orow + dt * 16 + c] = to_bf16(o[qsub][dt][r] * linv);
    }
}

// ---------------- output projection ----------------
// C = Ob[4096 x 1024] . woT[1024 x 1024]^T + bo, fp32 out. Tiles 128x64.
__global__ __launch_bounds__(256, 2) void out_gemm(
    const bf16_t* __restrict__ Ob, const bf16_t* __restrict__ woT,
    const float* __restrict__ bo, float* __restrict__ out) {
  __shared__ alignas(16) bf16_t lA[128 * 64];
  __shared__ alignas(16) bf16_t lB[64 * 64];
  f32x4 acc[4][2] = {};
  const int Mb = blockIdx.x * 128, Nb = blockIdx.y * 64;
  gemm_core<128, 64>(Ob + (size_t)Mb * Esz, woT + (size_t)Nb * Esz, Esz, lA, lB, acc);
  const int lane = threadIdx.x & 63, wvi = threadIdx.x >> 6;
  const int g = lane >> 4, c = lane & 15;
  const int wm = wvi >> 1, wn = wvi & 1;
#pragma unroll
  for (int nt = 0; nt < 2; nt++) {
    const int col = Nb + wn * 32 + nt * 16 + c;
    const float bias = bo[col];
#pragma unroll
    for (int mt = 0; mt < 4; mt++)
#pragma unroll
      for (int r = 0; r < 4; r++) {
        const int row = Mb + wm * 64 + mt * 16 + g * 4 + r;
        out[(size_t)row * Esz + col] = acc[mt][nt][r] + bias;
      }
  }
}

extern "C" void kernel_launch(void* const* d_in, const int* in_sizes, int n_in,
                              void* d_out, int out_size, void* d_ws, size_t ws_size,
                              hipStream_t stream) {
  const float* x = (const float*)d_in[0];
  const int* mask = (const int*)d_in[1];
  const float* wq = (const float*)d_in[2];
  const float* bq = (const float*)d_in[3];
  const float* wk = (const float*)d_in[4];
  const float* bk = (const float*)d_in[5];
  const float* wv = (const float*)d_in[6];
  const float* bv = (const float*)d_in[7];
  const float* wo = (const float*)d_in[8];
  const float* bo = (const float*)d_in[9];
  float* out = (float*)d_out;

  char* ws = (char*)d_ws;
  size_t off = 0;
  auto take = [&](size_t bytes) -> char* {
    char* p = ws + off;
    off += (bytes + 255) & ~(size_t)255;
    return p;
  };
  bf16_t* xb    = (bf16_t*)take((size_t)Bsz * Ssz * Esz * 2);
  bf16_t* wAll  = (bf16_t*)take((size_t)2 * Esz * Esz * 2);
  bf16_t* wAllV = (bf16_t*)take((size_t)Esz * Esz * 2);
  bf16_t* woT   = (bf16_t*)take((size_t)Esz * Esz * 2);
  bf16_t* qb    = (bf16_t*)take((size_t)Bsz * Hsz * Ssz * DHsz * 2);
  bf16_t* kb    = (bf16_t*)take((size_t)Bsz * Hsz * Ssz * DHsz * 2);
  bf16_t* vTb   = (bf16_t*)take((size_t)Bsz * Hsz * Ssz * DHsz * 2);
  bf16_t* Ob    = (bf16_t*)take((size_t)Bsz * Ssz * Esz * 2);
  float*  mfp   = (float*)take((size_t)Bsz * Ssz * 4);

  const int n4 = Bsz * Ssz * Esz / 4;
  cast_x4<<<(n4 + 255) / 256, 256, 0, stream>>>((const float4*)x, (uint2*)xb, n4);
  mask_f<<<(Bsz * Ssz + 255) / 256, 256, 0, stream>>>(mask, mfp, Bsz * Ssz);
  wtrans<<<dim3(Esz / 64, Hsz, 4), 256, 0, stream>>>(wq, wk, wv, wo, wAll, wAllV, woT);

  qk_gemm<<<dim3(Bsz * Ssz / 128, 2 * Esz / 128), 256, 0, stream>>>(xb, wAll, bq, bk, qb, kb);
  vt_gemm<<<dim3(Esz / 64, Ssz / 128, Bsz), 256, 0, stream>>>(xb, wAllV, bv, vTb);
  flash_attn<<<dim3(Hsz, Ssz / 128, Bsz), 256, 0, stream>>>(qb, kb, vTb, mfp, Ob);
  out_gemm<<<dim3(Bsz * Ssz / 128, Esz / 64), 256, 0, stream>>>(Ob, woT, bo, out);
}